// Round 9
// baseline (555.816 us; speedup 1.0000x reference)
//
#include <hip/hip_runtime.h>

// Palettized 3x3 VALID conv as implicit GEMM:
//   C[M=16*254*254, 64] = A[M, K=576] * B[K=576, 64],  K = (kh*3+kw)*64 + c
// Round-9: B-OPERAND THROUGH LDS. Request accounting (R8's FETCH-halved/
// time-flat null proved the wall is per-CU request processing, not HBM
// bytes/occupancy/MLP): B-reads from global were 4608 of ~6100 line-requests
// per block (4 waves x 18 kc x 4 nt x 16 lines). Fix: channel-split phases
// (R4 structure) with BOTH A-half (25.3 KB) and B-half (36.9 KB) resident in
// LDS; K-loop reads B via ds_read_b128 (zero TA/L2 involvement). Global B
// traffic drops 4x per block (staged once, 9 dwordx4/wave). LDS 62.2 KB ->
// 2 blocks/CU -- acceptable: R6 proved occupancy is not the lever.
// R7's staging (dwordx4 MLP) + slab epilogue kept verbatim; no XCD swizzle.

typedef __bf16 bf16x8 __attribute__((ext_vector_type(8)));
typedef float f32x4 __attribute__((ext_vector_type(4)));

union Frag {
    uint4 q;
    bf16x8 v;
};

// ---- B dequant/swizzle: Bws[s]  s = (kc*4 + nt)*64 + lane, 16B per slot.
// lane holds B[k = kc*32 + (lane>>4)*8 + j][o = nt*16 + (lane&15)], j=0..7
// with k = (kh*3+kw)*64 + c  ->  kc: r = kc>>1 fixed, c = (kc&1)*32 + (lane>>4)*8 + j.
__global__ __launch_bounds__(256) void dequant_B(
        const float* __restrict__ lut, const int* __restrict__ widx,
        uint4* __restrict__ Bws) {
    int s = blockIdx.x * 256 + threadIdx.x;   // 0..4607
    int l = s & 63;
    int nt = (s >> 6) & 3;
    int kc = s >> 8;
    if (kc >= 18) return;
    int r = kc >> 1;
    int kh = r / 3, kw = r - kh * 3;
    int o = nt * 16 + (l & 15);
    int c0 = (kc & 1) * 32 + (l >> 4) * 8;
    Frag f;
#pragma unroll
    for (int j = 0; j < 8; ++j) {
        int c = c0 + j;
        int idx = widx[((o * 64 + c) * 3 + kh) * 3 + kw];
        f.v[j] = (__bf16)lut[idx];
    }
    Bws[s] = f.q;
}

// LDS: [0..1583]  A-half: 4 local cblk x (6 rows x 66 cols) granules (16B each)
//      [1584..]   B-half: 36 slots (i=0..8, nt=0..3) x 64 lanes
#define A_PIX 396

__global__ __launch_bounds__(256, 2) void conv_mfma(
        const float* __restrict__ x, const float* __restrict__ bias,
        const uint4* __restrict__ Bws, float* __restrict__ out) {
    __shared__ uint4 lds[3888];           // 62208 B -> 2 blocks/CU
    uint4* ldsA = lds;
    uint4* ldsB = lds + 1584;
    unsigned* lds32 = (unsigned*)lds;

    int bx = blockIdx.x;
    int ow0 = (bx & 3) * 64;          // 0,64,128,192
    int oh0 = ((bx >> 2) & 63) * 4;   // 0..252
    int n = bx >> 8;                  // 0..15
    int t = threadIdx.x;

    const float* xn = x + (size_t)n * (64 * 256 * 256);

    int w = t >> 6;
    int l = t & 63;
    int l15 = l & 15, l4 = l >> 4;

    // tail-staging constants (cols 64,65: 4 cb x 6 rows x 2 cols = 48, t<48)
    int tl_cb  = t & 3;
    int tl_rc  = t >> 2;              // 0..11 for t<48
    int tl_rr  = tl_rc >> 1;
    int tl_col = 64 + (tl_rc & 1);
    int tl_xc  = ow0 + tl_col; if (tl_xc > 255) tl_xc = 255;

    f32x4 acc[4][4] = {};

    for (int h = 0; h < 2; ++h) {
        // ---- issue B-half loads first (wave w stages nt=w): 9 dwordx4
        uint4 breg[9];
#pragma unroll
        for (int i = 0; i < 9; ++i)
            breg[i] = Bws[((2 * i + h) * 4 + w) * 64 + l];

        // ---- A-half stage (R7 pattern): wave w -> local cblk w (global h*4+w)
        // lane = (colg=l15, chp=l4); per row lane loads float4 of 2 channels.
        {
            int colg = l15, chp = l4;
            const float* cbase = xn + ((h * 4 + w) * 8 + chp * 2) * 65536
                                 + ow0 + colg * 4;
            f32x4 f0[6], f1[6];
#pragma unroll
            for (int rr = 0; rr < 6; ++rr) {
                int y = oh0 + rr; if (y > 255) y = 255;
                const float* p = cbase + y * 256;
                f0[rr] = *(const f32x4*)(p);
                f1[rr] = *(const f32x4*)(p + 65536);
            }
#pragma unroll
            for (int rr = 0; rr < 6; ++rr) {
                int gbase = w * A_PIX + rr * 66 + colg * 4;
#pragma unroll
                for (int i = 0; i < 4; ++i) {
                    union { __bf16 hh[2]; unsigned u; } bp;
                    bp.hh[0] = (__bf16)f0[rr][i];
                    bp.hh[1] = (__bf16)f1[rr][i];
                    lds32[(gbase + i) * 4 + chp] = bp.u;
                }
            }
            // tail cols 64,65: local cblk tl_cb (global h*4+tl_cb)
            if (t < 48) {
                int y = oh0 + tl_rr; if (y > 255) y = 255;
                const float* src = xn + ((h * 4 + tl_cb) * 8) * 65536
                                   + y * 256 + tl_xc;
                Frag f;
#pragma unroll
                for (int j = 0; j < 8; ++j)
                    f.v[j] = (__bf16)src[j * 65536];
                ldsA[tl_cb * A_PIX + tl_rr * 66 + tl_col] = f.q;
            }
        }

        // ---- write B-half to LDS (stride-16B across lanes: conflict-free)
#pragma unroll
        for (int i = 0; i < 9; ++i)
            ldsB[(i * 4 + w) * 64 + l] = breg[i];

        __syncthreads();

        // ---- 9 kc chunks of parity h: kc = 2*i + h
        //      A channels (h*4+l4)*8+j == h*32 + l4*8 + j == B's c  (verified)
#pragma unroll
        for (int i = 0; i < 9; ++i) {
            int kh = i / 3, kw = i - kh * 3;     // block-uniform, compile-time
            int pix = (w + kh) * 66 + l15 + kw;

            Frag b[4];
#pragma unroll
            for (int nt = 0; nt < 4; ++nt)
                b[nt].q = ldsB[(i * 4 + nt) * 64 + l];

            Frag a[4];
#pragma unroll
            for (int mt = 0; mt < 4; ++mt)
                a[mt].q = ldsA[l4 * A_PIX + pix + mt * 16];

#pragma unroll
            for (int mt = 0; mt < 4; ++mt)
#pragma unroll
                for (int nt = 0; nt < 4; ++nt)
                    acc[mt][nt] = __builtin_amdgcn_mfma_f32_16x16x32_bf16(
                        a[mt].v, b[nt].v, acc[mt][nt], 0, 0, 0);
        }
        __syncthreads();   // protect LDS before re-stage (h=0) / slab (h=1)
    }

    // ---- epilogue: transpose acc through wave-private LDS slab so every
    // global store is 64 lanes x 4B contiguous (one 256B segment).
    // acc C/D layout: lane l holds out[o=nt*16+l15][oh0+w][ow0+mt*16+l4*4+rg].
    float* slab = (float*)lds + w * (16 * 65);   // 4160 B per wave, reused per nt

    int oh = oh0 + w;
    if (oh < 254) {
        float* orow = out + (((size_t)n * 64) * 254 + oh) * 254 + ow0;
        bool colok = (ow0 + l) < 254;
#pragma unroll
        for (int nt = 0; nt < 4; ++nt) {
            // scatter this nt's 16 values into slab[o16][ow64] (pitch 65)
#pragma unroll
            for (int mt = 0; mt < 4; ++mt)
#pragma unroll
                for (int rg = 0; rg < 4; ++rg)
                    slab[l15 * 65 + mt * 16 + l4 * 4 + rg] = acc[mt][nt][rg];
            // gather transposed: lane l = column ow0+l, row j = plane nt*16+j
#pragma unroll
            for (int j = 0; j < 16; ++j) {
                int o = nt * 16 + j;
                float v = slab[j * 65 + l] + bias[o];
                if (colok)
                    orow[(size_t)o * (254 * 254) + l] = v;
            }
        }
    }
}

extern "C" void kernel_launch(void* const* d_in, const int* in_sizes, int n_in,
                              void* d_out, int out_size, void* d_ws, size_t ws_size,
                              hipStream_t stream) {
    const float* x    = (const float*)d_in[0];
    const float* lut  = (const float*)d_in[1];
    const int*   widx = (const int*)d_in[2];
    const float* bias = (const float*)d_in[3];
    float* out = (float*)d_out;
    uint4* Bws = (uint4*)d_ws;   // needs 73728 B

    dequant_B<<<18, 256, 0, stream>>>(lut, widx, Bws);
    conv_mfma<<<4096, 256, 0, stream>>>(x, bias, (const uint4*)Bws, out);
}

// Round 10
// 526.042 us; speedup vs baseline: 1.0566x; 1.0566x over previous
//
#include <hip/hip_runtime.h>

// Palettized 3x3 VALID conv as implicit GEMM:
//   C[M=16*254*254, 64] = A[M, K=576] * B[K=576, 64],  K = (kh*3+kw)*64 + c
// Round-10: B THROUGH LDS, register-safe. R9 validated the request-path
// theory (B-fragment global reads = 75% of per-block line-requests) but
// spilled breg[9] held across A-staging (+430 MB parasitic traffic, WRITE
// 282->577). Fix: full-A in LDS (R7 staging verbatim) + per-kc B streaming
// through a double-buffered 4KB LDS chunk. Prefetch = ONE uint4/thread
// (4 VGPRs, one-iteration lifetime); ds_write lands after the 16 MFMAs
// (latency hidden); one barrier per kc. Global B-requests: 2304 -> 576
// lines/block. LDS 58880 B -> 2 blocks/CU (occupancy proven irrelevant, R6).
// No XCD swizzle (R8: FETCH halved, time worse -> requests, not bytes).

typedef __bf16 bf16x8 __attribute__((ext_vector_type(8)));
typedef float f32x4 __attribute__((ext_vector_type(4)));

union Frag {
    uint4 q;
    bf16x8 v;
};

// ---- B dequant/swizzle: Bws[s]  s = (kc*4 + nt)*64 + lane, 16B per slot.
// lane holds B[k = kc*32 + (lane>>4)*8 + j][o = nt*16 + (lane&15)], j=0..7
// with k = (kh*3+kw)*64 + c  ->  kc: r = kc>>1 fixed, c = (kc&1)*32 + (lane>>4)*8 + j.
__global__ __launch_bounds__(256) void dequant_B(
        const float* __restrict__ lut, const int* __restrict__ widx,
        uint4* __restrict__ Bws) {
    int s = blockIdx.x * 256 + threadIdx.x;   // 0..4607
    int l = s & 63;
    int nt = (s >> 6) & 3;
    int kc = s >> 8;
    if (kc >= 18) return;
    int r = kc >> 1;
    int kh = r / 3, kw = r - kh * 3;
    int o = nt * 16 + (l & 15);
    int c0 = (kc & 1) * 32 + (l >> 4) * 8;
    Frag f;
#pragma unroll
    for (int j = 0; j < 8; ++j) {
        int c = c0 + j;
        int idx = widx[((o * 64 + c) * 3 + kh) * 3 + kw];
        f.v[j] = (__bf16)lut[idx];
    }
    Bws[s] = f.q;
}

// LDS layout: ldsA[cblk][pix] as 16B granules; pix = row*66 + col (row 0..5, col 0..65)
// granule = 8 bf16 = channels cblk*8 .. cblk*8+7 of pixel (row,col);
// u32 word k of a granule = packed (ch 2k, ch 2k+1).
#define LDS_PIX 396

__global__ __launch_bounds__(256, 3) void conv_mfma(
        const float* __restrict__ x, const float* __restrict__ bias,
        const uint4* __restrict__ Bws, float* __restrict__ out) {
    __shared__ uint4 ldsA[8 * LDS_PIX];   // 50688 B
    __shared__ uint4 ldsB[2][256];        // 8192 B (double-buffered B chunk)
    unsigned* lds32 = (unsigned*)ldsA;

    int bx = blockIdx.x;
    int ow0 = (bx & 3) * 64;          // 0,64,128,192
    int oh0 = ((bx >> 2) & 63) * 4;   // 0..252
    int n = bx >> 8;                  // 0..15
    int t = threadIdx.x;

    const float* xn = x + (size_t)n * (64 * 256 * 256);

    int w = t >> 6;
    int l = t & 63;
    int l15 = l & 15, l4 = l >> 4;

    // ---- issue B chunk 0 load first (4 VGPRs, contiguous 4KB per block)
    uint4 bpre = Bws[t];

    // ---- stage x[n, 0:64, oh0:oh0+6, ow0:ow0+66] -> LDS (fp32 -> bf16)
    // (R7 staging verbatim: lane = (colg=l15, chp=l4); per cblk-row lane
    // loads float4 of channels chp*2, chp*2+1; 6 rows batched.)
    {
        int colg = l15;
        int chp  = l4;                 // 0..3
        const float* xw = xn + ow0 + colg * 4;
#pragma unroll
        for (int cc = 0; cc < 2; ++cc) {
            int cb = w + cc * 4;       // wave-uniform cblk
            const float* cbase = xw + (cb * 8 + chp * 2) * 65536;
            f32x4 f0[6], f1[6];
#pragma unroll
            for (int rr = 0; rr < 6; ++rr) {
                int y = oh0 + rr; if (y > 255) y = 255;
                const float* p = cbase + y * 256;
                f0[rr] = *(const f32x4*)(p);
                f1[rr] = *(const f32x4*)(p + 65536);
            }
#pragma unroll
            for (int rr = 0; rr < 6; ++rr) {
                int gbase = cb * LDS_PIX + rr * 66 + colg * 4;
#pragma unroll
                for (int i = 0; i < 4; ++i) {
                    union { __bf16 h[2]; unsigned u; } bp;
                    bp.h[0] = (__bf16)f0[rr][i];
                    bp.h[1] = (__bf16)f1[rr][i];
                    lds32[(gbase + i) * 4 + chp] = bp.u;
                }
            }
        }
        // tail: cols 64,65 (6 rows x 2 cols x 8 cblks = 96 granules), scalar path
        if (t < 96) {
            int cblk = t & 7;
            int rc = t >> 3;            // 0..11
            int rr = rc >> 1;
            int col2 = 64 + (rc & 1);
            int y = oh0 + rr; if (y > 255) y = 255;
            int xc = ow0 + col2; if (xc > 255) xc = 255;
            const float* src = xn + cblk * 8 * 65536 + y * 256 + xc;
            Frag f;
#pragma unroll
            for (int j = 0; j < 8; ++j)
                f.v[j] = (__bf16)src[j * 65536];
            ldsA[cblk * LDS_PIX + rr * 66 + col2] = f.q;
        }
    }
    // ---- commit B chunk 0 and sync
    ldsB[0][t] = bpre;
    __syncthreads();

    // ---- main GEMM: wave w handles oh row (oh0+w) x 64 ow x 64 O.
    // Both operands from LDS; per kc prefetch next B chunk (1 uint4/thread).
    f32x4 acc[4][4] = {};

#pragma unroll 2
    for (int kc = 0; kc < 18; ++kc) {
        uint4 bn;
        if (kc < 17)
            bn = Bws[(kc + 1) * 256 + t];          // issue early

        int r = kc >> 1;
        int kh = r / 3, kw = r - kh * 3;           // block-uniform
        int cblk = (kc & 1) * 4 + l4;
        int pix = (w + kh) * 66 + l15 + kw;

        Frag b[4];
#pragma unroll
        for (int nt = 0; nt < 4; ++nt)
            b[nt].q = ldsB[kc & 1][nt * 64 + l];

        Frag a[4];
#pragma unroll
        for (int mt = 0; mt < 4; ++mt)
            a[mt].q = ldsA[cblk * LDS_PIX + pix + mt * 16];

#pragma unroll
        for (int mt = 0; mt < 4; ++mt)
#pragma unroll
            for (int nt = 0; nt < 4; ++nt)
                acc[mt][nt] = __builtin_amdgcn_mfma_f32_16x16x32_bf16(
                    a[mt].v, b[nt].v, acc[mt][nt], 0, 0, 0);

        if (kc < 17)
            ldsB[(kc + 1) & 1][t] = bn;            // vmcnt wait lands here
        __syncthreads();                           // one barrier per kc
    }
    // (final loop barrier doubles as the pre-slab barrier: all ldsA/ldsB
    //  reads are complete before it.)

    // ---- epilogue: transpose acc through wave-private LDS slab so every
    // global store is 64 lanes x 4B contiguous (one 256B segment).
    // acc C/D layout: lane l holds out[o=nt*16+l15][oh0+w][ow0+mt*16+l4*4+rg].
    float* slab = (float*)ldsA + w * (16 * 65);   // 4160 B per wave, reused per nt

    int oh = oh0 + w;
    if (oh < 254) {
        float* orow = out + (((size_t)n * 64) * 254 + oh) * 254 + ow0;
        bool colok = (ow0 + l) < 254;
#pragma unroll
        for (int nt = 0; nt < 4; ++nt) {
            // scatter this nt's 16 values into slab[o16][ow64] (pitch 65)
#pragma unroll
            for (int mt = 0; mt < 4; ++mt)
#pragma unroll
                for (int rg = 0; rg < 4; ++rg)
                    slab[l15 * 65 + mt * 16 + l4 * 4 + rg] = acc[mt][nt][rg];
            // gather transposed: lane l = column ow0+l, row j = plane nt*16+j
#pragma unroll
            for (int j = 0; j < 16; ++j) {
                int o = nt * 16 + j;
                float v = slab[j * 65 + l] + bias[o];
                if (colok)
                    orow[(size_t)o * (254 * 254) + l] = v;
            }
        }
    }
}

extern "C" void kernel_launch(void* const* d_in, const int* in_sizes, int n_in,
                              void* d_out, int out_size, void* d_ws, size_t ws_size,
                              hipStream_t stream) {
    const float* x    = (const float*)d_in[0];
    const float* lut  = (const float*)d_in[1];
    const int*   widx = (const int*)d_in[2];
    const float* bias = (const float*)d_in[3];
    float* out = (float*)d_out;
    uint4* Bws = (uint4*)d_ws;   // needs 73728 B

    dequant_B<<<18, 256, 0, stream>>>(lut, widx, Bws);
    conv_mfma<<<4096, 256, 0, stream>>>(x, bias, (const uint4*)Bws, out);
}

// Round 11
// 512.609 us; speedup vs baseline: 1.0843x; 1.0262x over previous
//
#include <hip/hip_runtime.h>

// Palettized 3x3 VALID conv as implicit GEMM:
//   C[M=16*254*254, 64] = A[M, K=576] * B[K=576, 64],  K = (kh*3+kw)*64 + c
// Round-11: de-confound R8. R8 = {XCD swizzle} + {staging: 3-row-batched
// scalar loads + whole-granule ds_write_b128 (bank conflicts 1.8e7->6.9e6)}
// and regressed 195->205 vs R7. This round keeps R8's staging, drops the
// swizzle (single-variable vs R8). If swizzle was the regression -> new best
// ~190-196 with R7's one measured inefficiency (8-way scatter-write conflict)
// fixed. If staging was the regression -> R7 confirmed as design floor.
// Everything else identical to R7/R8: 18-kc loop (B from global, no barriers
// inside), slab epilogue (1-segment stores), 4096 blocks, 3 blocks/CU.

typedef __bf16 bf16x8 __attribute__((ext_vector_type(8)));
typedef float f32x4 __attribute__((ext_vector_type(4)));

union Frag {
    uint4 q;
    bf16x8 v;
};

// ---- B dequant/swizzle: Bws[s]  s = (kc*4 + nt)*64 + lane, 16B per slot.
// lane holds B[k = kc*32 + (lane>>4)*8 + j][o = nt*16 + (lane&15)], j=0..7
// with k = (kh*3+kw)*64 + c  ->  kc: r = kc>>1 fixed, c = (kc&1)*32 + (lane>>4)*8 + j.
__global__ __launch_bounds__(256) void dequant_B(
        const float* __restrict__ lut, const int* __restrict__ widx,
        uint4* __restrict__ Bws) {
    int s = blockIdx.x * 256 + threadIdx.x;   // 0..4607
    int l = s & 63;
    int nt = (s >> 6) & 3;
    int kc = s >> 8;
    if (kc >= 18) return;
    int r = kc >> 1;
    int kh = r / 3, kw = r - kh * 3;
    int o = nt * 16 + (l & 15);
    int c0 = (kc & 1) * 32 + (l >> 4) * 8;
    Frag f;
#pragma unroll
    for (int j = 0; j < 8; ++j) {
        int c = c0 + j;
        int idx = widx[((o * 64 + c) * 3 + kh) * 3 + kw];
        f.v[j] = (__bf16)lut[idx];
    }
    Bws[s] = f.q;
}

// LDS layout: ldsA[cblk][pix] as 16B granules; pix = row*66 + col (row 0..5, col 0..65)
// granule = 8 bf16 = channels cblk*8 .. cblk*8+7 of pixel (row,col).
#define LDS_PIX 396

__global__ __launch_bounds__(256, 3) void conv_mfma(
        const float* __restrict__ x, const float* __restrict__ bias,
        const uint4* __restrict__ Bws, float* __restrict__ out) {
    __shared__ uint4 ldsA[8 * LDS_PIX];   // 50688 B

    int bx = blockIdx.x;                  // natural order (no XCD swizzle)
    int ow0 = (bx & 3) * 64;          // 0,64,128,192
    int oh0 = ((bx >> 2) & 63) * 4;   // 0..252
    int n = bx >> 8;                  // 0..15
    int t = threadIdx.x;

    const float* xn = x + (size_t)n * (64 * 256 * 256);

    int w = t >> 6;
    int l = t & 63;
    int l15 = l & 15, l4 = l >> 4;

    // ---- stage x[n, 0:64, oh0:oh0+6, ow0:ow0+66] -> LDS (fp32 -> bf16)
    // lane l = col; wave w owns cblk {w, w+4}. Per half: 3 rows x 8 chans =
    // 24 independent scalar loads (each instr = 64 lanes x 4B = 1 segment),
    // then 3 contiguous ds_write_b128 (whole granule: conflict-free writes).
    {
        const float* colbase = xn + ow0 + l;
#pragma unroll
        for (int cp = 0; cp < 2; ++cp) {
            int cb = w + cp * 4;       // wave-uniform cblk
            const float* cb8 = colbase + cb * 8 * 65536;
#pragma unroll
            for (int half = 0; half < 2; ++half) {
                float f[3][8];
#pragma unroll
                for (int rr = 0; rr < 3; ++rr) {
                    int y = oh0 + half * 3 + rr; if (y > 255) y = 255;
                    const float* src = cb8 + y * 256;
#pragma unroll
                    for (int j = 0; j < 8; ++j)
                        f[rr][j] = src[j * 65536];
                }
#pragma unroll
                for (int rr = 0; rr < 3; ++rr) {
                    Frag fr;
#pragma unroll
                    for (int j = 0; j < 8; ++j)
                        fr.v[j] = (__bf16)f[rr][j];
                    ldsA[cb * LDS_PIX + (half * 3 + rr) * 66 + l] = fr.q;
                }
            }
        }
        // tail: cols 64,65 (6 rows x 2 cols x 8 cblks = 96 granules), scalar path
        if (t < 96) {
            int cblk = t & 7;
            int rc = t >> 3;            // 0..11
            int rr = rc >> 1;
            int col2 = 64 + (rc & 1);
            int y = oh0 + rr; if (y > 255) y = 255;
            int xc = ow0 + col2; if (xc > 255) xc = 255;
            const float* src = xn + cblk * 8 * 65536 + y * 256 + xc;
            Frag f;
#pragma unroll
            for (int j = 0; j < 8; ++j)
                f.v[j] = (__bf16)src[j * 65536];
            ldsA[cblk * LDS_PIX + rr * 66 + col2] = f.q;
        }
    }
    __syncthreads();

    // ---- main GEMM: wave w handles oh row (oh0+w) x 64 ow x 64 O
    f32x4 acc[4][4] = {};

    for (int kc = 0; kc < 18; ++kc) {
        int r = kc >> 1;
        int kh = r / 3, kw = r - kh * 3;       // block-uniform
        int cblk = (kc & 1) * 4 + l4;
        int pix = (w + kh) * 66 + l15 + kw;

        Frag b[4];
#pragma unroll
        for (int nt = 0; nt < 4; ++nt)
            b[nt].q = Bws[(kc * 4 + nt) * 64 + l];

        Frag a[4];
#pragma unroll
        for (int mt = 0; mt < 4; ++mt)
            a[mt].q = ldsA[cblk * LDS_PIX + pix + mt * 16];

#pragma unroll
        for (int mt = 0; mt < 4; ++mt)
#pragma unroll
            for (int nt = 0; nt < 4; ++nt)
                acc[mt][nt] = __builtin_amdgcn_mfma_f32_16x16x32_bf16(
                    a[mt].v, b[nt].v, acc[mt][nt], 0, 0, 0);
    }

    // ---- epilogue: transpose acc through wave-private LDS slab so every
    // global store is 64 lanes x 4B contiguous (one 256B segment).
    // acc C/D layout: lane l holds out[o=nt*16+l15][oh0+w][ow0+mt*16+l4*4+rg].
    __syncthreads();                       // everyone done reading ldsA
    float* slab = (float*)ldsA + w * (16 * 65);   // 4160 B per wave, reused per nt

    int oh = oh0 + w;
    if (oh < 254) {
        float* orow = out + (((size_t)n * 64) * 254 + oh) * 254 + ow0;
        bool colok = (ow0 + l) < 254;
#pragma unroll
        for (int nt = 0; nt < 4; ++nt) {
            // scatter this nt's 16 values into slab[o16][ow64] (pitch 65)
#pragma unroll
            for (int mt = 0; mt < 4; ++mt)
#pragma unroll
                for (int rg = 0; rg < 4; ++rg)
                    slab[l15 * 65 + mt * 16 + l4 * 4 + rg] = acc[mt][nt][rg];
            // gather transposed: lane l = column ow0+l, row j = plane nt*16+j
#pragma unroll
            for (int j = 0; j < 16; ++j) {
                int o = nt * 16 + j;
                float v = slab[j * 65 + l] + bias[o];
                if (colok)
                    orow[(size_t)o * (254 * 254) + l] = v;
            }
        }
    }
}

extern "C" void kernel_launch(void* const* d_in, const int* in_sizes, int n_in,
                              void* d_out, int out_size, void* d_ws, size_t ws_size,
                              hipStream_t stream) {
    const float* x    = (const float*)d_in[0];
    const float* lut  = (const float*)d_in[1];
    const int*   widx = (const int*)d_in[2];
    const float* bias = (const float*)d_in[3];
    float* out = (float*)d_out;
    uint4* Bws = (uint4*)d_ws;   // needs 73728 B

    dequant_B<<<18, 256, 0, stream>>>(lut, widx, Bws);
    conv_mfma<<<4096, 256, 0, stream>>>(x, bias, (const uint4*)Bws, out);
}

// Round 12
// 490.904 us; speedup vs baseline: 1.1322x; 1.0442x over previous
//
#include <hip/hip_runtime.h>

// Palettized 3x3 VALID conv as implicit GEMM:
//   C[M=16*254*254, 64] = A[M, K=576] * B[K=576, 64],  K = (kh*3+kw)*64 + c
// Round-12: DRAM-PAGE-DENSITY tile reshape. 12 experiments: BW pinned at
// 2.5-3.0 TB/s invariant to occupancy/MLP/requests/cache-tier; only page-
// dense streams (R2/R9 spill) ever exceeded it (3.8-4.1). Old tile touched
// DRAM in 256-264B fragments (26% of a 1KB row-stride). New tile 2oh x 128ow
// x 64O doubles every run: x-reads 520B/(row,ch), stores 512B dwordx2 with
// both oh rows of a plane adjacent. Activates/block: reads 384->256, writes
// 128->64. Channel-split (R4-verified) -> LDS 33.9KB -> 4 blocks/CU.
// Staging = R5 dwordx4 pattern (best measured); B from global; natural order.

typedef __bf16 bf16x8 __attribute__((ext_vector_type(8)));
typedef float f32x4 __attribute__((ext_vector_type(4)));
typedef float f32x2 __attribute__((ext_vector_type(2)));

union Frag {
    uint4 q;
    bf16x8 v;
};

// ---- B dequant/swizzle: Bws[s]  s = (kc*4 + nt)*64 + lane, 16B per slot.
// lane holds B[k = kc*32 + (lane>>4)*8 + j][o = nt*16 + (lane&15)], j=0..7
// with k = (kh*3+kw)*64 + c  ->  kc: r = kc>>1 fixed, c = (kc&1)*32 + (lane>>4)*8 + j.
__global__ __launch_bounds__(256) void dequant_B(
        const float* __restrict__ lut, const int* __restrict__ widx,
        uint4* __restrict__ Bws) {
    int s = blockIdx.x * 256 + threadIdx.x;   // 0..4607
    int l = s & 63;
    int nt = (s >> 6) & 3;
    int kc = s >> 8;
    if (kc >= 18) return;
    int r = kc >> 1;
    int kh = r / 3, kw = r - kh * 3;
    int o = nt * 16 + (l & 15);
    int c0 = (kc & 1) * 32 + (l >> 4) * 8;
    Frag f;
#pragma unroll
    for (int j = 0; j < 8; ++j) {
        int c = c0 + j;
        int idx = widx[((o * 64 + c) * 3 + kh) * 3 + kw];
        f.v[j] = (__bf16)lut[idx];
    }
    Bws[s] = f.q;
}

// LDS: ldsA[cbl][pix] 16B granules; pix = row*132 + col (row 0..3, col 0..129,
// pitch 132). cbl stride A_CB=530 granules (8480 B ≡ 32B mod 128: the four
// l4 read-groups land on different banks). granule = 8 bf16 channels.
#define A_CB 530

__global__ __launch_bounds__(256, 4) void conv_mfma(
        const float* __restrict__ x, const float* __restrict__ bias,
        const uint4* __restrict__ Bws, float* __restrict__ out) {
    __shared__ uint4 ldsA[4 * A_CB];      // 33920 B -> 4 blocks/CU
    unsigned* lds32 = (unsigned*)ldsA;

    int bx = blockIdx.x;                  // natural order
    int owt = bx & 1;
    int rem = bx >> 1;
    int ohp = rem % 127;                  // 0..126
    int n   = rem / 127;                  // 0..15
    int ow0 = owt * 128;                  // 0,128
    int oh0 = ohp * 2;                    // 0..252  (covers oh0, oh0+1)
    int t = threadIdx.x;

    const float* xn = x + (size_t)n * (64 * 256 * 256);

    int w = t >> 6;                       // wave 0..3
    int l = t & 63;
    int l15 = l & 15, l4 = l >> 4;

    // tail staging (cols 128,129): per half 4 cbl x 4 row x 2 col = 32, t<32
    int tl_cb  = t & 3;
    int tl_rc  = t >> 2;                  // 0..7 for t<32
    int tl_rr  = tl_rc >> 1;              // 0..3
    int tl_col = 128 + (tl_rc & 1);
    int tl_xc  = ow0 + tl_col; if (tl_xc > 255) tl_xc = 255;

    int ohl = w >> 1;                     // wave's oh row in tile (0..1)
    int ob  = (w & 1) * 2;                // wave's B nt-offset (O-half)

    f32x4 acc[8][2] = {};

    for (int h = 0; h < 2; ++h) {
        // ---- stage x[n, h*32:(h+1)*32, oh0:oh0+4, ow0:ow0+130] -> LDS
        // wave w -> cblk w of half h (8 channels). lane = (colg=l15, chp=l4:
        // channel pair 2*l4,2*l4+1). Per col-half ch2: 4 rows x 2 planes
        // dwordx4 (8 loads, 520B/row-fragment page runs), pack u32 pairs.
        {
            const float* cbase = xn + (size_t)(((h * 4 + w) * 8 + l4 * 2)) * 65536
                                 + ow0;
#pragma unroll
            for (int ch2 = 0; ch2 < 2; ++ch2) {
                const float* pb = cbase + ch2 * 64 + l15 * 4;
                f32x4 f0[4], f1[4];
#pragma unroll
                for (int rr = 0; rr < 4; ++rr) {
                    const float* p = pb + (oh0 + rr) * 256;
                    f0[rr] = *(const f32x4*)(p);
                    f1[rr] = *(const f32x4*)(p + 65536);
                }
#pragma unroll
                for (int rr = 0; rr < 4; ++rr) {
                    int gbase = w * A_CB + rr * 132 + ch2 * 64 + l15 * 4;
#pragma unroll
                    for (int i = 0; i < 4; ++i) {
                        union { __bf16 hh[2]; unsigned u; } bp;
                        bp.hh[0] = (__bf16)f0[rr][i];
                        bp.hh[1] = (__bf16)f1[rr][i];
                        lds32[(gbase + i) * 4 + l4] = bp.u;
                    }
                }
            }
            if (t < 32) {
                const float* src = xn + (size_t)((h * 4 + tl_cb) * 8) * 65536
                                   + (oh0 + tl_rr) * 256 + tl_xc;
                Frag f;
#pragma unroll
                for (int j = 0; j < 8; ++j)
                    f.v[j] = (__bf16)src[j * 65536];
                ldsA[tl_cb * A_CB + tl_rr * 132 + tl_col] = f.q;
            }
        }
        __syncthreads();

        // ---- 9 kc chunks of parity h: kc = 2*i + h (r = i).
        // A channels (h*4+l4)*8+j == h*32+l4*8+j == B's c  (same as R4).
#pragma unroll
        for (int i = 0; i < 9; ++i) {
            int kh = i / 3, kw = i - kh * 3;     // compile-time
            int kc = 2 * i + h;

            Frag b[2];
#pragma unroll
            for (int nt = 0; nt < 2; ++nt)
                b[nt].q = Bws[(kc * 4 + ob + nt) * 64 + l];

            Frag a[8];
#pragma unroll
            for (int mt = 0; mt < 8; ++mt)
                a[mt].q = ldsA[l4 * A_CB + (ohl + kh) * 132 + l15 + kw + mt * 16];

#pragma unroll
            for (int mt = 0; mt < 8; ++mt)
#pragma unroll
                for (int nt = 0; nt < 2; ++nt)
                    acc[mt][nt] = __builtin_amdgcn_mfma_f32_16x16x32_bf16(
                        a[mt].v, b[nt].v, acc[mt][nt], 0, 0, 0);
        }
        __syncthreads();   // h=0: protect before restage; h=1: before slab reuse
    }

    // ---- epilogue: slab transpose (R7 pattern, verified) -> dwordx2 stores.
    // acc C/D: lane l holds out[o=oseg+nt*16+l15][oh0+ohl][ow0+mt*16+l4*4+rg].
    // After transpose lane l covers cols l*2, l*2+1 -> 512B/instr page runs.
    float* slab = (float*)ldsA + w * (16 * 130);   // 8320 B per wave
    int oseg = (w & 1) * 32;
    int oh = oh0 + ohl;                            // always < 254
    float* orow = out + ((size_t)n * 64 * 254 + oh) * 254 + ow0;
    bool ok = (ow0 + l * 2 + 1) < 254;
#pragma unroll
    for (int nt = 0; nt < 2; ++nt) {
        // scatter this nt's 32 values into slab[o16][ow128] (pitch 130)
#pragma unroll
        for (int mt = 0; mt < 8; ++mt)
#pragma unroll
            for (int rg = 0; rg < 4; ++rg)
                slab[l15 * 130 + mt * 16 + l4 * 4 + rg] = acc[mt][nt][rg];
        // gather transposed: lane l -> cols l*2,l*2+1; row j -> plane oseg+nt*16+j
#pragma unroll
        for (int j = 0; j < 16; ++j) {
            int o = oseg + nt * 16 + j;
            float bv = bias[o];
            f32x2 v;
            v[0] = slab[j * 130 + l * 2]     + bv;
            v[1] = slab[j * 130 + l * 2 + 1] + bv;
            if (ok)
                *(f32x2*)(orow + (size_t)o * (254 * 254) + l * 2) = v;
        }
    }
}

extern "C" void kernel_launch(void* const* d_in, const int* in_sizes, int n_in,
                              void* d_out, int out_size, void* d_ws, size_t ws_size,
                              hipStream_t stream) {
    const float* x    = (const float*)d_in[0];
    const float* lut  = (const float*)d_in[1];
    const int*   widx = (const int*)d_in[2];
    const float* bias = (const float*)d_in[3];
    float* out = (float*)d_out;
    uint4* Bws = (uint4*)d_ws;   // needs 73728 B

    dequant_B<<<18, 256, 0, stream>>>(lut, widx, Bws);
    conv_mfma<<<16 * 127 * 2, 256, 0, stream>>>(x, bias, (const uint4*)Bws, out);
}